// Round 7
// baseline (140.546 us; speedup 1.0000x reference)
//
#include <hip/hip_runtime.h>
#include <math.h>

// RelativeAttention on MI355X (gfx950). FP32 inputs/output; bf16 intermediates, fp32 accum.
// Round 23: attn K/V LDS staging ELIMINATED — fragments loaded global->register directly.
// The stage-swizzle (sgcol) and read-swizzle (kcol/g0/g1) telescope: kf0=K[c*32+l15][quad*8],
// kf1=+16 rows, v fragments = V^T[{l15,16+l15}][c*32+{0,16}+quad*4]. Per chunk per wave:
// 6 global loads replace {4 DMA + 6 ds_read + lgkm drain + swizzle math}; attn uses zero LDS.
// Register double-buffer by chunk parity (named sets, no runtime indexing), 9 loads/chunk
// (6 K/V + 3 bias) -> steady vmcnt(9), prologue 18, tail traced. Math bit-identical to R20
// (absmax canary 0.06640625). prep reverted to R20-exact (R22 float4 prep cost +1.25us).
// Ledger: attn issue-cuts pay 1:1 (R19/R20); latency restructures null; added sync negative.
// B=8, C=256, H=W=32 (L=1024), nh=8, dk=dv=32, OUT_C=256.

typedef unsigned short u16;
typedef __bf16 bf16;
typedef bf16 bf16x8 __attribute__((ext_vector_type(8)));
typedef bf16 bf16x4 __attribute__((ext_vector_type(4)));
typedef short s16x4 __attribute__((ext_vector_type(4)));
typedef float f32x4 __attribute__((ext_vector_type(4)));
typedef float f32x4u __attribute__((ext_vector_type(4), aligned(4)));
typedef u16 u16x8 __attribute__((ext_vector_type(8)));
typedef u16 u16x4 __attribute__((ext_vector_type(4)));

#define DEVI __device__ __forceinline__

DEVI u16 bfbits(float f) { return __builtin_bit_cast(u16, (bf16)f); }

DEVI void async_cp16(const u16* g, u16* l) {
    __builtin_amdgcn_global_load_lds((const __attribute__((address_space(1))) void*)g,
                                     (__attribute__((address_space(3))) void*)l, 16, 0, 0);
}

// 16x16x16 bf16 MFMA (K=16): A[m=lane&15][k=quad*4+j], B[k=quad*4+j][n=lane&15],
// C/D[row=quad*4+reg][col=lane&15]. (absmax-verified R7-R20.)
DEVI f32x4 pv_mfma(bf16x4 a, bf16x4 b, f32x4 c) {
#if __has_builtin(__builtin_amdgcn_mfma_f32_16x16x16bf16_1k)
    return __builtin_amdgcn_mfma_f32_16x16x16bf16_1k(
        __builtin_bit_cast(s16x4, a), __builtin_bit_cast(s16x4, b), c, 0, 0, 0);
#else
    asm("s_nop 1\n\tv_mfma_f32_16x16x16_bf16 %0, %1, %2, %0"
        : "+v"(c) : "v"(a), "v"(b));
    return c;
#endif
}

// ---------------- fused prep: transposes + bias prescale (R20-exact) ----------------
__global__ __launch_bounds__(256) void prep(const float* __restrict__ X,
                                            const float* __restrict__ Qw, const float* __restrict__ Kw,
                                            const float* __restrict__ Vw, const float* __restrict__ Fw,
                                            const float* __restrict__ RB,
                                            u16* __restrict__ XF, u16* __restrict__ WT,
                                            float* __restrict__ RBs) {
    __shared__ u16 t[64 * 65];
    const int blk = blockIdx.x, tid = threadIdx.x;
    if (blk < 576) {
        const float* src;
        int cbase, rbase, rows_total;
        u16* dst;
        if (blk < 512) {
            const int b = blk >> 6;
            cbase = (blk & 3) * 64; rbase = ((blk >> 2) & 15) * 64;
            src = X + (size_t)b * 256 * 1024; dst = XF + (size_t)b * 1024 * 256;
            rows_total = 1024;
        } else {
            const int t2 = blk - 512, wsel = t2 >> 4;
            cbase = (t2 & 3) * 64; rbase = ((t2 >> 2) & 3) * 64;
            src = wsel == 0 ? Qw : wsel == 1 ? Kw : wsel == 2 ? Vw : Fw;
            dst = WT + (size_t)wsel * 256 * 256;
            rows_total = 256;
        }
        const int w = tid >> 6, r = tid & 63;
#pragma unroll
        for (int i = 0; i < 16; i++) {
            const int c = w * 16 + i;
            t[c * 65 + r] = bfbits(src[(size_t)(cbase + c) * rows_total + rbase + r]);
        }
        __syncthreads();
#pragma unroll
        for (int i = 0; i < 2; i++) {
            const int idx = i * 256 + tid;
            const int r2 = idx >> 3, cg = idx & 7;
            u16x8 v;
#pragma unroll
            for (int j = 0; j < 8; j++) v[j] = t[(cg * 8 + j) * 65 + r2];
            *(u16x8*)&dst[(size_t)(rbase + r2) * 256 + cbase + cg * 8] = v;
        }
    } else {
        const int n = 8 * 3969;
        for (int i = (blk - 576) * 256 + tid; i < n; i += 32 * 256)
            RBs[i] = RB[i] * 1.44269504f;
    }
}

// ---------------- unified GEMM: D[m][n] = sum_k A[m][k]*Bt[n][k], K=256, bf16 in ----------------
// Tile (MFR*32) x 64, BK=32; 4 waves as 2x2, wave = (MFR*16) x 32. async_cp16 staging +
// XOR-swizzled chunks. R17: double-buffered LDS, prefetch-then-compute, ONE barrier/K-iter.
// PASS 0: blocks 0..511 mode 0 (xf*wt -> q,k), 512..767 mode 1 (Vw^T*xf -> v^T). MFR=4.
// PASS 2: FF (ffw^T*ob -> fp32 out + bias). MFR=2, 512 blocks.
template <int MFR, int PASS>
__global__ __launch_bounds__(256, 3) void gemm_fused(const u16* __restrict__ xf, const u16* __restrict__ wt,
                                                     u16* __restrict__ q, u16* __restrict__ kk,
                                                     u16* __restrict__ vt, const u16* __restrict__ ob,
                                                     float* __restrict__ outf, const float* __restrict__ ffb) {
    constexpr int TM = MFR * 32;                       // block M-span
    __shared__ __align__(16) u16 lA[2][TM * 32];
    __shared__ __align__(16) u16 lB[2][64 * 32];
    const int tid = threadIdx.x;
    const int wave = tid >> 6, lane = tid & 63;
    const int quad = lane >> 4, l15 = lane & 15;

    int mode, mbase, nbase;
    const u16 *A, *Bt;
    if (PASS == 2) {
        mode = 2; A = wt + 768 * 256; Bt = ob;               // M=256, N=8192
        mbase = (blockIdx.x & 3) * 64; nbase = (blockIdx.x >> 2) * 64;
    } else if (blockIdx.x < 512) {
        mode = 0; A = xf; Bt = wt;                            // M=8192, N=512
        mbase = (blockIdx.x >> 3) * TM; nbase = (blockIdx.x & 7) * 64;
    } else {
        mode = 1; A = wt + 512 * 256; Bt = xf;                // M=256, N=8192
        const int t = blockIdx.x - 512;
        mbase = (t & 1) * TM; nbase = (t >> 1) * 64;
    }

    const int m0 = (wave >> 1) * (MFR * 16), n0 = (wave & 1) * 32;
    const int srow = tid >> 2;                         // wave*16 + lane>>2: rows per 64-row half
    const int sgcol = (lane & 3) ^ ((lane >> 3) & 3);  // swizzled global chunk col (64-row invariant)
    const int kcol = ((quad ^ ((l15 >> 1) & 3))) * 8;  // reader chunk (16-row-base invariant)

    f32x4 acc[MFR][2];
#pragma unroll
    for (int i = 0; i < MFR; i++)
#pragma unroll
        for (int j = 0; j < 2; j++) acc[i][j] = f32x4{0.f, 0.f, 0.f, 0.f};

    // prologue: stage K-tile 0 into buffer 0, drain, barrier
#pragma unroll
    for (int half = 0; half < MFR / 2; half++)
        async_cp16(&A[(size_t)(mbase + half * 64 + srow) * 256 + sgcol * 8],
                   &lA[0][half * 2048 + wave * 512]);
    async_cp16(&Bt[(size_t)(nbase + srow) * 256 + sgcol * 8], &lB[0][wave * 512]);
    __syncthreads();

#pragma unroll
    for (int t = 0; t < 8; ++t) {
        const int cur = t & 1;
        if (t < 7) {                                    // prefetch next K-tile into the other buffer
            const int kb = (t + 1) * 32;
#pragma unroll
            for (int half = 0; half < MFR / 2; half++)
                async_cp16(&A[(size_t)(mbase + half * 64 + srow) * 256 + kb + sgcol * 8],
                           &lA[cur ^ 1][half * 2048 + wave * 512]);
            async_cp16(&Bt[(size_t)(nbase + srow) * 256 + kb + sgcol * 8], &lB[cur ^ 1][wave * 512]);
        }
        bf16x8 af[MFR], bfr[2];
#pragma unroll
        for (int i = 0; i < MFR; i++) af[i] = *(const bf16x8*)&lA[cur][(m0 + i * 16 + l15) * 32 + kcol];
#pragma unroll
        for (int j = 0; j < 2; j++) bfr[j] = *(const bf16x8*)&lB[cur][(n0 + j * 16 + l15) * 32 + kcol];
#pragma unroll
        for (int i = 0; i < MFR; i++)
#pragma unroll
            for (int j = 0; j < 2; j++)
                acc[i][j] = __builtin_amdgcn_mfma_f32_16x16x32_bf16(af[i], bfr[j], acc[i][j], 0, 0, 0);
        __syncthreads();   // vmcnt(0)+lgkmcnt(0)+barrier: next buffer ready, reads of cur done
    }

    // epilogue: C-layout col = lane&15, row = quad*4 + reg
#pragma unroll
    for (int i = 0; i < MFR; i++) {
#pragma unroll
        for (int j = 0; j < 2; j++) {
#pragma unroll
            for (int r = 0; r < 4; r++) {
                const int gm = mbase + m0 + i * 16 + quad * 4 + r;
                const int gn = nbase + n0 + j * 16 + l15;
                float v = acc[i][j][r];
                if (mode == 0) {
                    const int b = gm >> 10, l = gm & 1023;
                    int n = gn;
                    u16* dst = q;
                    if (n >= 256) { n -= 256; dst = kk; }
                    else v *= 1.44269504f;                 // fold log2e into q
                    const int h = n >> 5, d = n & 31;
                    dst[(((size_t)(b * 8 + h) * 1024 + l) << 5) + d] = bfbits(v);
                } else if (mode == 1) {
                    const int h = gm >> 5, d = gm & 31;
                    const int b = gn >> 10, l = gn & 1023;
                    vt[(((size_t)(b * 8 + h) * 32 + d) << 10) + l] = bfbits(v);
                } else {
                    const int b = gn >> 10, l = gn & 1023;
                    outf[(((size_t)(b * 256 + gm)) << 10) + l] = v + ffb[gm];
                }
            }
        }
    }
}

// ---------------- flash attention: zero-LDS, global->register fragments ----------------
// 512 blocks x 4 waves x 32 q-rows. R23: K/V/bias loaded straight into named register sets
// (even/odd chunk parity), 9 loads per chunk per wave, steady vmcnt(9) depth-2 pipeline.
// R19: bias as QK^T C-operand. R20: denominator via pv_mfma(p, ones, sac).
__global__ __launch_bounds__(256, 2) void attn(const u16* __restrict__ Q, const u16* __restrict__ Kb,
                                               const u16* __restrict__ Vt, const float* __restrict__ RBs,
                                               u16* __restrict__ O) {
    const int tid = threadIdx.x;
    const int wave = tid >> 6, lane = tid & 63;
    const int quad = lane >> 4, l15 = lane & 15;
    const int blk = blockIdx.x;
    const int bh = ((blk >> 6) << 3) + (blk & 7);       // XCD swizzle
    const int qt = (blk >> 3) & 7;
    const int b = bh >> 3, h = bh & 7;
    const int qbase = qt * 128 + wave * 32;
    const size_t bhL = (size_t)bh * 1024;

    const bf16x8 qfA = *(const bf16x8*)&Q[(bhL + qbase + l15) * 32 + quad * 8];
    const bf16x8 qfB = *(const bf16x8*)&Q[(bhL + qbase + 16 + l15) * 32 + quad * 8];
    const float* brow0 = RBs + (size_t)h * 3969
                         + (32 - (qbase >> 5)) * 32 + 32 - l15 + quad * 4;
    // direct fragment base pointers (swizzle chain telescoped):
    const u16* kr0 = &Kb[bhL * 32] + (size_t)l15 * 32 + quad * 8;        // K[l15][quad*8..]
    const u16* kr1 = kr0 + 16 * 32;                                      // K[16+l15][...]
    const u16* vr_lo = &Vt[((size_t)(bh * 32) + l15) << 10] + quad * 4;  // V^T[l15][quad*4..]
    const u16* vr_hi = vr_lo + (16 << 10);                               // V^T[16+l15][...]

    f32x4 oA_lo{0.f, 0.f, 0.f, 0.f}, oA_hi{0.f, 0.f, 0.f, 0.f};
    f32x4 oB_lo{0.f, 0.f, 0.f, 0.f}, oB_hi{0.f, 0.f, 0.f, 0.f};
    f32x4 sacA{0.f, 0.f, 0.f, 0.f}, sacB{0.f, 0.f, 0.f, 0.f};  // denom: row=quad*4+r == q row
    const bf16 one1 = (bf16)1.f;
    const bf16x4 onesb = {one1, one1, one1, one1};

    // register sets, chunk parity 0/1 (named: no runtime indexing -> stays in VGPRs)
    bf16x8 k0_0, k1_0, k0_1, k1_1;
    bf16x4 va_0, vb_0, vc_0, vd_0, va_1, vb_1, vc_1, vd_1;
    f32x4u bm_0, b0_0, b1_0, bm_1, b0_1, b1_1;

#define LOADS(P, c) do {                                                        \
        const int kb_ = (c) * 32;                                               \
        k0_##P = *(const bf16x8*)(kr0 + (size_t)kb_ * 32);                      \
        k1_##P = *(const bf16x8*)(kr1 + (size_t)kb_ * 32);                      \
        va_##P = *(const bf16x4*)(vr_lo + kb_);                                 \
        vb_##P = *(const bf16x4*)(vr_lo + kb_ + 16);                            \
        vc_##P = *(const bf16x4*)(vr_hi + kb_);                                 \
        vd_##P = *(const bf16x4*)(vr_hi + kb_ + 16);                            \
        bm_##P = *(const f32x4u*)(brow0 + (c) * 32 - 16);                       \
        b0_##P = *(const f32x4u*)(brow0 + (c) * 32);                            \
        b1_##P = *(const f32x4u*)(brow0 + (c) * 32 + 16);                       \
    } while (0)

// Bias rides in as the QK^T C-operand (R19). Denominator via sac MFMAs (R20).
#define COMPUTE(P) do {                                                                   \
        f32x4 s0A = __builtin_amdgcn_mfma_f32_16x16x32_bf16(k0_##P, qfA, __builtin_bit_cast(f32x4, b0_##P), 0, 0, 0); \
        f32x4 s1A = __builtin_amdgcn_mfma_f32_16x16x32_bf16(k1_##P, qfA, __builtin_bit_cast(f32x4, b1_##P), 0, 0, 0); \
        f32x4 s0B = __builtin_amdgcn_mfma_f32_16x16x32_bf16(k0_##P, qfB, __builtin_bit_cast(f32x4, bm_##P), 0, 0, 0); \
        f32x4 s1B = __builtin_amdgcn_mfma_f32_16x16x32_bf16(k1_##P, qfB, __builtin_bit_cast(f32x4, b0_##P), 0, 0, 0); \
        bf16x4 p0A, p1A, p0B, p1B;                                                        \
        _Pragma("unroll")                                                                 \
        for (int r = 0; r < 4; r++) {                                                     \
            p0A[r] = (bf16)__builtin_amdgcn_exp2f(s0A[r]);                                \
            p1A[r] = (bf16)__builtin_amdgcn_exp2f(s1A[r]);                                \
            p0B[r] = (bf16)__builtin_amdgcn_exp2f(s0B[r]);                                \
            p1B[r] = (bf16)__builtin_amdgcn_exp2f(s1B[r]);                                \
        }                                                                                 \
        oA_lo = pv_mfma(p0A, va_##P, oA_lo);                                              \
        oA_hi = pv_mfma(p0A, vc_##P, oA_hi);                                              \
        oA_lo = pv_mfma(p1A, vb_##P, oA_lo);                                              \
        oA_hi = pv_mfma(p1A, vd_##P, oA_hi);                                              \
        sacA = pv_mfma(p0A, onesb, sacA);                                                 \
        sacA = pv_mfma(p1A, onesb, sacA);                                                 \
        oB_lo = pv_mfma(p0B, va_##P, oB_lo);                                              \
        oB_hi = pv_mfma(p0B, vc_##P, oB_hi);                                              \
        oB_lo = pv_mfma(p1B, vb_##P, oB_lo);                                              \
        oB_hi = pv_mfma(p1B, vd_##P, oB_hi);                                              \
        sacB = pv_mfma(p0B, onesb, sacB);                                                 \
        sacB = pv_mfma(p1B, onesb, sacB);                                                 \
    } while (0)

#define WAIT9 asm volatile("s_waitcnt vmcnt(9)" ::: "memory")
#define WAIT0 asm volatile("s_waitcnt vmcnt(0)" ::: "memory")

    // prologue: chunks 0,1 in flight (18). Steady state: WAIT9 completes the older chunk's 9.
    LOADS(0, 0);
    LOADS(1, 1);
    for (int c = 0; c < 28; c += 2) {
        WAIT9; COMPUTE(0); LOADS(0, c + 2);
        WAIT9; COMPUTE(1); LOADS(1, c + 3);
    }
    WAIT9; COMPUTE(0); LOADS(0, 30);
    WAIT9; COMPUTE(1); LOADS(1, 31);
    WAIT9; COMPUTE(0);
    WAIT0; COMPUTE(1);
#undef LOADS
#undef COMPUTE
#undef WAIT9
#undef WAIT0

    // sac[r] = full denominator for q row quad*4+r (replicated over l15) — direct reciprocal.
#pragma unroll
    for (int r = 0; r < 4; r++) {
        const float invA = 1.f / sacA[r];
        const float invB = 1.f / sacB[r];
        const int iA = qbase + quad * 4 + r;
        const int iB = iA + 16;
        O[((size_t)(b * 1024 + iA) * 256) + h * 32 + l15] = bfbits(oA_lo[r] * invA);
        O[((size_t)(b * 1024 + iA) * 256) + h * 32 + 16 + l15] = bfbits(oA_hi[r] * invA);
        O[((size_t)(b * 1024 + iB) * 256) + h * 32 + l15] = bfbits(oB_lo[r] * invB);
        O[((size_t)(b * 1024 + iB) * 256) + h * 32 + 16 + l15] = bfbits(oB_hi[r] * invB);
    }
}

extern "C" void kernel_launch(void* const* d_in, const int* in_sizes, int n_in,
                              void* d_out, int out_size, void* d_ws, size_t ws_size,
                              hipStream_t stream) {
    const float* x   = (const float*)d_in[0];
    const float* Qw  = (const float*)d_in[1];
    const float* Kw  = (const float*)d_in[2];
    const float* Vw  = (const float*)d_in[3];
    const float* Fw  = (const float*)d_in[4];
    const float* ffb = (const float*)d_in[5];
    const float* RB  = (const float*)d_in[6];
    // d_in[7] = rel_idx (int32): deterministic, computed analytically in-kernel.

    u16* ws = (u16*)d_ws;
    u16* xf = ws;                   // 8192 x 256 bf16 (4 MB)   ... later reused as ob
    u16* wt = xf + 2097152;         // 1024 x 256 bf16 (0.5 MB) [Qw^T|Kw^T|Vw^T|ffw^T]
    u16* q  = wt + 262144;          // (b,h,l,d)  bf16 (4 MB), pre-scaled by log2e
    u16* kk = q  + 2097152;         // (b,h,l,d)  bf16 (4 MB)
    u16* vt = kk + 2097152;         // (b,h,d,l)  bf16 (4 MB)
    float* RBs = (float*)(vt + 2097152);   // 8 x 3969 fp32 (127 KB), bias * log2e
    u16* ob = xf;                   // (b,l,h*32+d) bf16 — aliases xf (dead after V proj)

    prep<<<dim3(608), 256, 0, stream>>>(x, Qw, Kw, Vw, Fw, RB, xf, wt, RBs);
    gemm_fused<4, 0><<<dim3(768), 256, 0, stream>>>(xf, wt, q, kk, vt, nullptr, nullptr, nullptr); // QK + V^T
    attn<<<dim3(512), 256, 0, stream>>>(q, kk, vt, RBs, ob);
    gemm_fused<2, 2><<<dim3(512), 256, 0, stream>>>(xf, wt, q, kk, vt, ob, (float*)d_out, ffb);    // FF
}

// Round 8
// 139.995 us; speedup vs baseline: 1.0039x; 1.0039x over previous
//
#include <hip/hip_runtime.h>
#include <math.h>

// RelativeAttention on MI355X (gfx950). FP32 inputs/output; bf16 intermediates, fp32 accum.
// Round 24: attn zero-LDS pipeline deepened 2 -> 4 chunks. R23 counters (first direct attn
// visibility): 50.4us, MfmaUtil 12%, VALUBusy 15.7%, occupancy 17.5%, 0 bank conflicts,
// FETCH 6.2MB -> pure latency-bound on K/V loads served from remote-XCD L2 / L3 (~600cyc;
// gemm wrote q/kk/vt on other XCDs). Depth-2 gave only ~1 COMPUTE (~200cyc) of cover.
// Depth-4 named register sets: 36 loads in flight, WAIT27 completes the chunk issued 3
// COMPUTE phases (~600+cyc) earlier; tail 27/18/9/0 (FIFO traced). VGPR ~124 (<256, still
// 2 waves/SIMD). Math identical (absmax canary 0.06640625). prep=R20-exact, gemm=R17.
// B=8, C=256, H=W=32 (L=1024), nh=8, dk=dv=32, OUT_C=256.

typedef unsigned short u16;
typedef __bf16 bf16;
typedef bf16 bf16x8 __attribute__((ext_vector_type(8)));
typedef bf16 bf16x4 __attribute__((ext_vector_type(4)));
typedef short s16x4 __attribute__((ext_vector_type(4)));
typedef float f32x4 __attribute__((ext_vector_type(4)));
typedef float f32x4u __attribute__((ext_vector_type(4), aligned(4)));
typedef u16 u16x8 __attribute__((ext_vector_type(8)));
typedef u16 u16x4 __attribute__((ext_vector_type(4)));

#define DEVI __device__ __forceinline__

DEVI u16 bfbits(float f) { return __builtin_bit_cast(u16, (bf16)f); }

DEVI void async_cp16(const u16* g, u16* l) {
    __builtin_amdgcn_global_load_lds((const __attribute__((address_space(1))) void*)g,
                                     (__attribute__((address_space(3))) void*)l, 16, 0, 0);
}

// 16x16x16 bf16 MFMA (K=16): A[m=lane&15][k=quad*4+j], B[k=quad*4+j][n=lane&15],
// C/D[row=quad*4+reg][col=lane&15]. (absmax-verified R7-R20.)
DEVI f32x4 pv_mfma(bf16x4 a, bf16x4 b, f32x4 c) {
#if __has_builtin(__builtin_amdgcn_mfma_f32_16x16x16bf16_1k)
    return __builtin_amdgcn_mfma_f32_16x16x16bf16_1k(
        __builtin_bit_cast(s16x4, a), __builtin_bit_cast(s16x4, b), c, 0, 0, 0);
#else
    asm("s_nop 1\n\tv_mfma_f32_16x16x16_bf16 %0, %1, %2, %0"
        : "+v"(c) : "v"(a), "v"(b));
    return c;
#endif
}

// ---------------- fused prep: transposes + bias prescale (R20-exact) ----------------
__global__ __launch_bounds__(256) void prep(const float* __restrict__ X,
                                            const float* __restrict__ Qw, const float* __restrict__ Kw,
                                            const float* __restrict__ Vw, const float* __restrict__ Fw,
                                            const float* __restrict__ RB,
                                            u16* __restrict__ XF, u16* __restrict__ WT,
                                            float* __restrict__ RBs) {
    __shared__ u16 t[64 * 65];
    const int blk = blockIdx.x, tid = threadIdx.x;
    if (blk < 576) {
        const float* src;
        int cbase, rbase, rows_total;
        u16* dst;
        if (blk < 512) {
            const int b = blk >> 6;
            cbase = (blk & 3) * 64; rbase = ((blk >> 2) & 15) * 64;
            src = X + (size_t)b * 256 * 1024; dst = XF + (size_t)b * 1024 * 256;
            rows_total = 1024;
        } else {
            const int t2 = blk - 512, wsel = t2 >> 4;
            cbase = (t2 & 3) * 64; rbase = ((t2 >> 2) & 3) * 64;
            src = wsel == 0 ? Qw : wsel == 1 ? Kw : wsel == 2 ? Vw : Fw;
            dst = WT + (size_t)wsel * 256 * 256;
            rows_total = 256;
        }
        const int w = tid >> 6, r = tid & 63;
#pragma unroll
        for (int i = 0; i < 16; i++) {
            const int c = w * 16 + i;
            t[c * 65 + r] = bfbits(src[(size_t)(cbase + c) * rows_total + rbase + r]);
        }
        __syncthreads();
#pragma unroll
        for (int i = 0; i < 2; i++) {
            const int idx = i * 256 + tid;
            const int r2 = idx >> 3, cg = idx & 7;
            u16x8 v;
#pragma unroll
            for (int j = 0; j < 8; j++) v[j] = t[(cg * 8 + j) * 65 + r2];
            *(u16x8*)&dst[(size_t)(rbase + r2) * 256 + cbase + cg * 8] = v;
        }
    } else {
        const int n = 8 * 3969;
        for (int i = (blk - 576) * 256 + tid; i < n; i += 32 * 256)
            RBs[i] = RB[i] * 1.44269504f;
    }
}

// ---------------- unified GEMM: D[m][n] = sum_k A[m][k]*Bt[n][k], K=256, bf16 in ----------------
// Tile (MFR*32) x 64, BK=32; 4 waves as 2x2, wave = (MFR*16) x 32. async_cp16 staging +
// XOR-swizzled chunks. R17: double-buffered LDS, prefetch-then-compute, ONE barrier/K-iter.
// PASS 0: blocks 0..511 mode 0 (xf*wt -> q,k), 512..767 mode 1 (Vw^T*xf -> v^T). MFR=4.
// PASS 2: FF (ffw^T*ob -> fp32 out + bias). MFR=2, 512 blocks.
template <int MFR, int PASS>
__global__ __launch_bounds__(256, 3) void gemm_fused(const u16* __restrict__ xf, const u16* __restrict__ wt,
                                                     u16* __restrict__ q, u16* __restrict__ kk,
                                                     u16* __restrict__ vt, const u16* __restrict__ ob,
                                                     float* __restrict__ outf, const float* __restrict__ ffb) {
    constexpr int TM = MFR * 32;                       // block M-span
    __shared__ __align__(16) u16 lA[2][TM * 32];
    __shared__ __align__(16) u16 lB[2][64 * 32];
    const int tid = threadIdx.x;
    const int wave = tid >> 6, lane = tid & 63;
    const int quad = lane >> 4, l15 = lane & 15;

    int mode, mbase, nbase;
    const u16 *A, *Bt;
    if (PASS == 2) {
        mode = 2; A = wt + 768 * 256; Bt = ob;               // M=256, N=8192
        mbase = (blockIdx.x & 3) * 64; nbase = (blockIdx.x >> 2) * 64;
    } else if (blockIdx.x < 512) {
        mode = 0; A = xf; Bt = wt;                            // M=8192, N=512
        mbase = (blockIdx.x >> 3) * TM; nbase = (blockIdx.x & 7) * 64;
    } else {
        mode = 1; A = wt + 512 * 256; Bt = xf;                // M=256, N=8192
        const int t = blockIdx.x - 512;
        mbase = (t & 1) * TM; nbase = (t >> 1) * 64;
    }

    const int m0 = (wave >> 1) * (MFR * 16), n0 = (wave & 1) * 32;
    const int srow = tid >> 2;                         // wave*16 + lane>>2: rows per 64-row half
    const int sgcol = (lane & 3) ^ ((lane >> 3) & 3);  // swizzled global chunk col (64-row invariant)
    const int kcol = ((quad ^ ((l15 >> 1) & 3))) * 8;  // reader chunk (16-row-base invariant)

    f32x4 acc[MFR][2];
#pragma unroll
    for (int i = 0; i < MFR; i++)
#pragma unroll
        for (int j = 0; j < 2; j++) acc[i][j] = f32x4{0.f, 0.f, 0.f, 0.f};

    // prologue: stage K-tile 0 into buffer 0, drain, barrier
#pragma unroll
    for (int half = 0; half < MFR / 2; half++)
        async_cp16(&A[(size_t)(mbase + half * 64 + srow) * 256 + sgcol * 8],
                   &lA[0][half * 2048 + wave * 512]);
    async_cp16(&Bt[(size_t)(nbase + srow) * 256 + sgcol * 8], &lB[0][wave * 512]);
    __syncthreads();

#pragma unroll
    for (int t = 0; t < 8; ++t) {
        const int cur = t & 1;
        if (t < 7) {                                    // prefetch next K-tile into the other buffer
            const int kb = (t + 1) * 32;
#pragma unroll
            for (int half = 0; half < MFR / 2; half++)
                async_cp16(&A[(size_t)(mbase + half * 64 + srow) * 256 + kb + sgcol * 8],
                           &lA[cur ^ 1][half * 2048 + wave * 512]);
            async_cp16(&Bt[(size_t)(nbase + srow) * 256 + kb + sgcol * 8], &lB[cur ^ 1][wave * 512]);
        }
        bf16x8 af[MFR], bfr[2];
#pragma unroll
        for (int i = 0; i < MFR; i++) af[i] = *(const bf16x8*)&lA[cur][(m0 + i * 16 + l15) * 32 + kcol];
#pragma unroll
        for (int j = 0; j < 2; j++) bfr[j] = *(const bf16x8*)&lB[cur][(n0 + j * 16 + l15) * 32 + kcol];
#pragma unroll
        for (int i = 0; i < MFR; i++)
#pragma unroll
            for (int j = 0; j < 2; j++)
                acc[i][j] = __builtin_amdgcn_mfma_f32_16x16x32_bf16(af[i], bfr[j], acc[i][j], 0, 0, 0);
        __syncthreads();   // vmcnt(0)+lgkmcnt(0)+barrier: next buffer ready, reads of cur done
    }

    // epilogue: C-layout col = lane&15, row = quad*4 + reg
#pragma unroll
    for (int i = 0; i < MFR; i++) {
#pragma unroll
        for (int j = 0; j < 2; j++) {
#pragma unroll
            for (int r = 0; r < 4; r++) {
                const int gm = mbase + m0 + i * 16 + quad * 4 + r;
                const int gn = nbase + n0 + j * 16 + l15;
                float v = acc[i][j][r];
                if (mode == 0) {
                    const int b = gm >> 10, l = gm & 1023;
                    int n = gn;
                    u16* dst = q;
                    if (n >= 256) { n -= 256; dst = kk; }
                    else v *= 1.44269504f;                 // fold log2e into q
                    const int h = n >> 5, d = n & 31;
                    dst[(((size_t)(b * 8 + h) * 1024 + l) << 5) + d] = bfbits(v);
                } else if (mode == 1) {
                    const int h = gm >> 5, d = gm & 31;
                    const int b = gn >> 10, l = gn & 1023;
                    vt[(((size_t)(b * 8 + h) * 32 + d) << 10) + l] = bfbits(v);
                } else {
                    const int b = gn >> 10, l = gn & 1023;
                    outf[(((size_t)(b * 256 + gm)) << 10) + l] = v + ffb[gm];
                }
            }
        }
    }
}

// ---------------- flash attention: zero-LDS, global->register, depth-4 pipeline ----------
// 512 blocks x 4 waves x 32 q-rows. R24: 4 named register sets, 36 loads in flight,
// WAIT27 steady state (oldest chunk issued 3 COMPUTE phases earlier).
// R19: bias as QK^T C-operand. R20: denominator via pv_mfma(p, ones, sac).
__global__ __launch_bounds__(256, 2) void attn(const u16* __restrict__ Q, const u16* __restrict__ Kb,
                                               const u16* __restrict__ Vt, const float* __restrict__ RBs,
                                               u16* __restrict__ O) {
    const int tid = threadIdx.x;
    const int wave = tid >> 6, lane = tid & 63;
    const int quad = lane >> 4, l15 = lane & 15;
    const int blk = blockIdx.x;
    const int bh = ((blk >> 6) << 3) + (blk & 7);       // XCD swizzle
    const int qt = (blk >> 3) & 7;
    const int b = bh >> 3, h = bh & 7;
    const int qbase = qt * 128 + wave * 32;
    const size_t bhL = (size_t)bh * 1024;

    const bf16x8 qfA = *(const bf16x8*)&Q[(bhL + qbase + l15) * 32 + quad * 8];
    const bf16x8 qfB = *(const bf16x8*)&Q[(bhL + qbase + 16 + l15) * 32 + quad * 8];
    const float* brow0 = RBs + (size_t)h * 3969
                         + (32 - (qbase >> 5)) * 32 + 32 - l15 + quad * 4;
    // direct fragment base pointers (swizzle chain telescoped):
    const u16* kr0 = &Kb[bhL * 32] + (size_t)l15 * 32 + quad * 8;        // K[l15][quad*8..]
    const u16* kr1 = kr0 + 16 * 32;                                      // K[16+l15][...]
    const u16* vr_lo = &Vt[((size_t)(bh * 32) + l15) << 10] + quad * 4;  // V^T[l15][quad*4..]
    const u16* vr_hi = vr_lo + (16 << 10);                               // V^T[16+l15][...]

    f32x4 oA_lo{0.f, 0.f, 0.f, 0.f}, oA_hi{0.f, 0.f, 0.f, 0.f};
    f32x4 oB_lo{0.f, 0.f, 0.f, 0.f}, oB_hi{0.f, 0.f, 0.f, 0.f};
    f32x4 sacA{0.f, 0.f, 0.f, 0.f}, sacB{0.f, 0.f, 0.f, 0.f};  // denom: row=quad*4+r == q row
    const bf16 one1 = (bf16)1.f;
    const bf16x4 onesb = {one1, one1, one1, one1};

    // register sets, chunk mod 4 (named: no runtime indexing -> stays in VGPRs)
    bf16x8 k0_0, k1_0, k0_1, k1_1, k0_2, k1_2, k0_3, k1_3;
    bf16x4 va_0, vb_0, vc_0, vd_0, va_1, vb_1, vc_1, vd_1;
    bf16x4 va_2, vb_2, vc_2, vd_2, va_3, vb_3, vc_3, vd_3;
    f32x4u bm_0, b0_0, b1_0, bm_1, b0_1, b1_1, bm_2, b0_2, b1_2, bm_3, b0_3, b1_3;

#define LOADS(P, c) do {                                                        \
        const int kb_ = (c) * 32;                                               \
        k0_##P = *(const bf16x8*)(kr0 + (size_t)kb_ * 32);                      \
        k1_##P = *(const bf16x8*)(kr1 + (size_t)kb_ * 32);                      \
        va_##P = *(const bf16x4*)(vr_lo + kb_);                                 \
        vb_##P = *(const bf16x4*)(vr_lo + kb_ + 16);                            \
        vc_##P = *(const bf16x4*)(vr_hi + kb_);                                 \
        vd_##P = *(const bf16x4*)(vr_hi + kb_ + 16);                            \
        bm_##P = *(const f32x4u*)(brow0 + (c) * 32 - 16);                       \
        b0_##P = *(const f32x4u*)(brow0 + (c) * 32);                            \
        b1_##P = *(const f32x4u*)(brow0 + (c) * 32 + 16);                       \
    } while (0)

// Bias rides in as the QK^T C-operand (R19). Denominator via sac MFMAs (R20).
#define COMPUTE(P) do {                                                                   \
        f32x4 s0A = __builtin_amdgcn_mfma_f32_16x16x32_bf16(k0_##P, qfA, __builtin_bit_cast(f32x4, b0_##P), 0, 0, 0); \
        f32x4 s1A = __builtin_amdgcn_mfma_f32_16x16x32_bf16(k1_##P, qfA, __builtin_bit_cast(f32x4, b1_##P), 0, 0, 0); \
        f32x4 s0B = __builtin_amdgcn_mfma_f32_16x16x32_bf16(k0_##P, qfB, __builtin_bit_cast(f32x4, bm_##P), 0, 0, 0); \
        f32x4 s1B = __builtin_amdgcn_mfma_f32_16x16x32_bf16(k1_##P, qfB, __builtin_bit_cast(f32x4, b0_##P), 0, 0, 0); \
        bf16x4 p0A, p1A, p0B, p1B;                                                        \
        _Pragma("unroll")                                                                 \
        for (int r = 0; r < 4; r++) {                                                     \
            p0A[r] = (bf16)__builtin_amdgcn_exp2f(s0A[r]);                                \
            p1A[r] = (bf16)__builtin_amdgcn_exp2f(s1A[r]);                                \
            p0B[r] = (bf16)__builtin_amdgcn_exp2f(s0B[r]);                                \
            p1B[r] = (bf16)__builtin_amdgcn_exp2f(s1B[r]);                                \
        }                                                                                 \
        oA_lo = pv_mfma(p0A, va_##P, oA_lo);                                              \
        oA_hi = pv_mfma(p0A, vc_##P, oA_hi);                                              \
        oA_lo = pv_mfma(p1A, vb_##P, oA_lo);                                              \
        oA_hi = pv_mfma(p1A, vd_##P, oA_hi);                                              \
        sacA = pv_mfma(p0A, onesb, sacA);                                                 \
        sacA = pv_mfma(p1A, onesb, sacA);                                                 \
        oB_lo = pv_mfma(p0B, va_##P, oB_lo);                                              \
        oB_hi = pv_mfma(p0B, vc_##P, oB_hi);                                              \
        oB_lo = pv_mfma(p1B, vb_##P, oB_lo);                                              \
        oB_hi = pv_mfma(p1B, vd_##P, oB_hi);                                              \
        sacB = pv_mfma(p0B, onesb, sacB);                                                 \
        sacB = pv_mfma(p1B, onesb, sacB);                                                 \
    } while (0)

#define WAIT27 asm volatile("s_waitcnt vmcnt(27)" ::: "memory")
#define WAIT18 asm volatile("s_waitcnt vmcnt(18)" ::: "memory")
#define WAIT9  asm volatile("s_waitcnt vmcnt(9)" ::: "memory")
#define WAIT0  asm volatile("s_waitcnt vmcnt(0)" ::: "memory")

    // prologue: chunks 0..3 in flight (36 loads). Steady: WAIT27 completes the oldest chunk,
    // issued 3 COMPUTE phases (~600+ cyc) earlier.
    LOADS(0, 0);
    LOADS(1, 1);
    LOADS(2, 2);
    LOADS(3, 3);
    for (int c = 0; c < 28; c += 4) {
        WAIT27; COMPUTE(0); LOADS(0, c + 4);
        WAIT27; COMPUTE(1); LOADS(1, c + 5);
        WAIT27; COMPUTE(2); LOADS(2, c + 6);
        WAIT27; COMPUTE(3); LOADS(3, c + 7);
    }
    // tail: chunks 28..31 outstanding (36 loads) -> drain 27/18/9/0.
    WAIT27; COMPUTE(0);
    WAIT18; COMPUTE(1);
    WAIT9;  COMPUTE(2);
    WAIT0;  COMPUTE(3);
#undef LOADS
#undef COMPUTE
#undef WAIT27
#undef WAIT18
#undef WAIT9
#undef WAIT0

    // sac[r] = full denominator for q row quad*4+r (replicated over l15) — direct reciprocal.
#pragma unroll
    for (int r = 0; r < 4; r++) {
        const float invA = 1.f / sacA[r];
        const float invB = 1.f / sacB[r];
        const int iA = qbase + quad * 4 + r;
        const int iB = iA + 16;
        O[((size_t)(b * 1024 + iA) * 256) + h * 32 + l15] = bfbits(oA_lo[r] * invA);
        O[((size_t)(b * 1024 + iA) * 256) + h * 32 + 16 + l15] = bfbits(oA_hi[r] * invA);
        O[((size_t)(b * 1024 + iB) * 256) + h * 32 + l15] = bfbits(oB_lo[r] * invB);
        O[((size_t)(b * 1024 + iB) * 256) + h * 32 + 16 + l15] = bfbits(oB_hi[r] * invB);
    }
}

extern "C" void kernel_launch(void* const* d_in, const int* in_sizes, int n_in,
                              void* d_out, int out_size, void* d_ws, size_t ws_size,
                              hipStream_t stream) {
    const float* x   = (const float*)d_in[0];
    const float* Qw  = (const float*)d_in[1];
    const float* Kw  = (const float*)d_in[2];
    const float* Vw  = (const float*)d_in[3];
    const float* Fw  = (const float*)d_in[4];
    const float* ffb = (const float*)d_in[5];
    const float* RB  = (const float*)d_in[6];
    // d_in[7] = rel_idx (int32): deterministic, computed analytically in-kernel.

    u16* ws = (u16*)d_ws;
    u16* xf = ws;                   // 8192 x 256 bf16 (4 MB)   ... later reused as ob
    u16* wt = xf + 2097152;         // 1024 x 256 bf16 (0.5 MB) [Qw^T|Kw^T|Vw^T|ffw^T]
    u16* q  = wt + 262144;          // (b,h,l,d)  bf16 (4 MB), pre-scaled by log2e
    u16* kk = q  + 2097152;         // (b,h,l,d)  bf16 (4 MB)
    u16* vt = kk + 2097152;         // (b,h,d,l)  bf16 (4 MB)
    float* RBs = (float*)(vt + 2097152);   // 8 x 3969 fp32 (127 KB), bias * log2e
    u16* ob = xf;                   // (b,l,h*32+d) bf16 — aliases xf (dead after V proj)

    prep<<<dim3(608), 256, 0, stream>>>(x, Qw, Kw, Vw, Fw, RB, xf, wt, RBs);
    gemm_fused<4, 0><<<dim3(768), 256, 0, stream>>>(xf, wt, q, kk, vt, nullptr, nullptr, nullptr); // QK + V^T
    attn<<<dim3(512), 256, 0, stream>>>(q, kk, vt, RBs, ob);
    gemm_fused<2, 2><<<dim3(512), 256, 0, stream>>>(xf, wt, q, kk, vt, ob, (float*)d_out, ffb);    // FF
}

// Round 9
// 118.374 us; speedup vs baseline: 1.1873x; 1.1826x over previous
//
#include <hip/hip_runtime.h>
#include <math.h>

// RelativeAttention on MI355X (gfx950). FP32 inputs/output; bf16 intermediates, fp32 accum.
// Round 25: full restore of the R20 optimum (116.35us, absmax 0.06640625) + T5 s_setprio
// around attn's MFMA/exp2 compute burst (m191: +4-7% on phase-staggered multi-wave attn).
// R23/R24 lesson: zero-LDS direct gathers are ~2x slower than cp16 DMA staging and
// insensitive to pipeline depth (48.7us, both pipes 85% idle) -> reverted for good.
// Ledger: attn issue-cuts pay 1:1 (R19/R20); structural rewrites lose (R21/R23/R24);
// prep/gemm restructures null or negative (R17/R18/R22).
// B=8, C=256, H=W=32 (L=1024), nh=8, dk=dv=32, OUT_C=256.

typedef unsigned short u16;
typedef __bf16 bf16;
typedef bf16 bf16x8 __attribute__((ext_vector_type(8)));
typedef bf16 bf16x4 __attribute__((ext_vector_type(4)));
typedef short s16x4 __attribute__((ext_vector_type(4)));
typedef float f32x4 __attribute__((ext_vector_type(4)));
typedef float f32x4u __attribute__((ext_vector_type(4), aligned(4)));
typedef u16 u16x8 __attribute__((ext_vector_type(8)));
typedef u16 u16x4 __attribute__((ext_vector_type(4)));

#define DEVI __device__ __forceinline__

DEVI u16 bfbits(float f) { return __builtin_bit_cast(u16, (bf16)f); }

DEVI void async_cp16(const u16* g, u16* l) {
    __builtin_amdgcn_global_load_lds((const __attribute__((address_space(1))) void*)g,
                                     (__attribute__((address_space(3))) void*)l, 16, 0, 0);
}

// 16x16x16 bf16 MFMA (K=16): A[m=lane&15][k=quad*4+j], B[k=quad*4+j][n=lane&15],
// C/D[row=quad*4+reg][col=lane&15]. (absmax-verified R7-R20.)
DEVI f32x4 pv_mfma(bf16x4 a, bf16x4 b, f32x4 c) {
#if __has_builtin(__builtin_amdgcn_mfma_f32_16x16x16bf16_1k)
    return __builtin_amdgcn_mfma_f32_16x16x16bf16_1k(
        __builtin_bit_cast(s16x4, a), __builtin_bit_cast(s16x4, b), c, 0, 0, 0);
#else
    asm("s_nop 1\n\tv_mfma_f32_16x16x16_bf16 %0, %1, %2, %0"
        : "+v"(c) : "v"(a), "v"(b));
    return c;
#endif
}

// ---------------- fused prep: transposes + bias prescale (R20-exact) ----------------
__global__ __launch_bounds__(256) void prep(const float* __restrict__ X,
                                            const float* __restrict__ Qw, const float* __restrict__ Kw,
                                            const float* __restrict__ Vw, const float* __restrict__ Fw,
                                            const float* __restrict__ RB,
                                            u16* __restrict__ XF, u16* __restrict__ WT,
                                            float* __restrict__ RBs) {
    __shared__ u16 t[64 * 65];
    const int blk = blockIdx.x, tid = threadIdx.x;
    if (blk < 576) {
        const float* src;
        int cbase, rbase, rows_total;
        u16* dst;
        if (blk < 512) {
            const int b = blk >> 6;
            cbase = (blk & 3) * 64; rbase = ((blk >> 2) & 15) * 64;
            src = X + (size_t)b * 256 * 1024; dst = XF + (size_t)b * 1024 * 256;
            rows_total = 1024;
        } else {
            const int t2 = blk - 512, wsel = t2 >> 4;
            cbase = (t2 & 3) * 64; rbase = ((t2 >> 2) & 3) * 64;
            src = wsel == 0 ? Qw : wsel == 1 ? Kw : wsel == 2 ? Vw : Fw;
            dst = WT + (size_t)wsel * 256 * 256;
            rows_total = 256;
        }
        const int w = tid >> 6, r = tid & 63;
#pragma unroll
        for (int i = 0; i < 16; i++) {
            const int c = w * 16 + i;
            t[c * 65 + r] = bfbits(src[(size_t)(cbase + c) * rows_total + rbase + r]);
        }
        __syncthreads();
#pragma unroll
        for (int i = 0; i < 2; i++) {
            const int idx = i * 256 + tid;
            const int r2 = idx >> 3, cg = idx & 7;
            u16x8 v;
#pragma unroll
            for (int j = 0; j < 8; j++) v[j] = t[(cg * 8 + j) * 65 + r2];
            *(u16x8*)&dst[(size_t)(rbase + r2) * 256 + cbase + cg * 8] = v;
        }
    } else {
        const int n = 8 * 3969;
        for (int i = (blk - 576) * 256 + tid; i < n; i += 32 * 256)
            RBs[i] = RB[i] * 1.44269504f;
    }
}

// ---------------- unified GEMM: D[m][n] = sum_k A[m][k]*Bt[n][k], K=256, bf16 in ----------------
// Tile (MFR*32) x 64, BK=32; 4 waves as 2x2, wave = (MFR*16) x 32. async_cp16 staging +
// XOR-swizzled chunks. R17: double-buffered LDS, prefetch-then-compute, ONE barrier/K-iter.
// PASS 0: blocks 0..511 mode 0 (xf*wt -> q,k), 512..767 mode 1 (Vw^T*xf -> v^T). MFR=4.
// PASS 2: FF (ffw^T*ob -> fp32 out + bias). MFR=2, 512 blocks.
template <int MFR, int PASS>
__global__ __launch_bounds__(256, 3) void gemm_fused(const u16* __restrict__ xf, const u16* __restrict__ wt,
                                                     u16* __restrict__ q, u16* __restrict__ kk,
                                                     u16* __restrict__ vt, const u16* __restrict__ ob,
                                                     float* __restrict__ outf, const float* __restrict__ ffb) {
    constexpr int TM = MFR * 32;                       // block M-span
    __shared__ __align__(16) u16 lA[2][TM * 32];
    __shared__ __align__(16) u16 lB[2][64 * 32];
    const int tid = threadIdx.x;
    const int wave = tid >> 6, lane = tid & 63;
    const int quad = lane >> 4, l15 = lane & 15;

    int mode, mbase, nbase;
    const u16 *A, *Bt;
    if (PASS == 2) {
        mode = 2; A = wt + 768 * 256; Bt = ob;               // M=256, N=8192
        mbase = (blockIdx.x & 3) * 64; nbase = (blockIdx.x >> 2) * 64;
    } else if (blockIdx.x < 512) {
        mode = 0; A = xf; Bt = wt;                            // M=8192, N=512
        mbase = (blockIdx.x >> 3) * TM; nbase = (blockIdx.x & 7) * 64;
    } else {
        mode = 1; A = wt + 512 * 256; Bt = xf;                // M=256, N=8192
        const int t = blockIdx.x - 512;
        mbase = (t & 1) * TM; nbase = (t >> 1) * 64;
    }

    const int m0 = (wave >> 1) * (MFR * 16), n0 = (wave & 1) * 32;
    const int srow = tid >> 2;                         // wave*16 + lane>>2: rows per 64-row half
    const int sgcol = (lane & 3) ^ ((lane >> 3) & 3);  // swizzled global chunk col (64-row invariant)
    const int kcol = ((quad ^ ((l15 >> 1) & 3))) * 8;  // reader chunk (16-row-base invariant)

    f32x4 acc[MFR][2];
#pragma unroll
    for (int i = 0; i < MFR; i++)
#pragma unroll
        for (int j = 0; j < 2; j++) acc[i][j] = f32x4{0.f, 0.f, 0.f, 0.f};

    // prologue: stage K-tile 0 into buffer 0, drain, barrier
#pragma unroll
    for (int half = 0; half < MFR / 2; half++)
        async_cp16(&A[(size_t)(mbase + half * 64 + srow) * 256 + sgcol * 8],
                   &lA[0][half * 2048 + wave * 512]);
    async_cp16(&Bt[(size_t)(nbase + srow) * 256 + sgcol * 8], &lB[0][wave * 512]);
    __syncthreads();

#pragma unroll
    for (int t = 0; t < 8; ++t) {
        const int cur = t & 1;
        if (t < 7) {                                    // prefetch next K-tile into the other buffer
            const int kb = (t + 1) * 32;
#pragma unroll
            for (int half = 0; half < MFR / 2; half++)
                async_cp16(&A[(size_t)(mbase + half * 64 + srow) * 256 + kb + sgcol * 8],
                           &lA[cur ^ 1][half * 2048 + wave * 512]);
            async_cp16(&Bt[(size_t)(nbase + srow) * 256 + kb + sgcol * 8], &lB[cur ^ 1][wave * 512]);
        }
        bf16x8 af[MFR], bfr[2];
#pragma unroll
        for (int i = 0; i < MFR; i++) af[i] = *(const bf16x8*)&lA[cur][(m0 + i * 16 + l15) * 32 + kcol];
#pragma unroll
        for (int j = 0; j < 2; j++) bfr[j] = *(const bf16x8*)&lB[cur][(n0 + j * 16 + l15) * 32 + kcol];
#pragma unroll
        for (int i = 0; i < MFR; i++)
#pragma unroll
            for (int j = 0; j < 2; j++)
                acc[i][j] = __builtin_amdgcn_mfma_f32_16x16x32_bf16(af[i], bfr[j], acc[i][j], 0, 0, 0);
        __syncthreads();   // vmcnt(0)+lgkmcnt(0)+barrier: next buffer ready, reads of cur done
    }

    // epilogue: C-layout col = lane&15, row = quad*4 + reg
#pragma unroll
    for (int i = 0; i < MFR; i++) {
#pragma unroll
        for (int j = 0; j < 2; j++) {
#pragma unroll
            for (int r = 0; r < 4; r++) {
                const int gm = mbase + m0 + i * 16 + quad * 4 + r;
                const int gn = nbase + n0 + j * 16 + l15;
                float v = acc[i][j][r];
                if (mode == 0) {
                    const int b = gm >> 10, l = gm & 1023;
                    int n = gn;
                    u16* dst = q;
                    if (n >= 256) { n -= 256; dst = kk; }
                    else v *= 1.44269504f;                 // fold log2e into q
                    const int h = n >> 5, d = n & 31;
                    dst[(((size_t)(b * 8 + h) * 1024 + l) << 5) + d] = bfbits(v);
                } else if (mode == 1) {
                    const int h = gm >> 5, d = gm & 31;
                    const int b = gn >> 10, l = gn & 1023;
                    vt[(((size_t)(b * 8 + h) * 32 + d) << 10) + l] = bfbits(v);
                } else {
                    const int b = gn >> 10, l = gn & 1023;
                    outf[(((size_t)(b * 256 + gm)) << 10) + l] = v + ffb[gm];
                }
            }
        }
    }
}

// ---------------- flash attention: 2 Q-tiles per wave, barrier-free depth-2 pipeline ----------
// 512 blocks x 4 waves x 32 q-rows. Per-wave private K/V LDS double-buffers, XOR swizzle,
// STAGE-after-COMPUTE + lgkm drain. Bias identity b1(tileB)==b0(tileA).
// R18: bias prefetched one chunk ahead (vmcnt(7) steady state). R19: bias as QK^T C-operand.
// R20: denominator via pv_mfma(p, ones, sac). R25: s_setprio(1) around the compute burst
// (T5/m191: CU scheduler favors compute-phase waves over staging-phase waves).
__global__ __launch_bounds__(256, 2) void attn(const u16* __restrict__ Q, const u16* __restrict__ Kb,
                                               const u16* __restrict__ Vt, const float* __restrict__ RBs,
                                               u16* __restrict__ O) {
    __shared__ __align__(16) u16 kbuf[4][2][32 * 32];
    __shared__ __align__(16) u16 vbuf[4][2][32 * 32];
    const int tid = threadIdx.x;
    const int wave = tid >> 6, lane = tid & 63;
    const int quad = lane >> 4, l15 = lane & 15;
    const int blk = blockIdx.x;
    const int bh = ((blk >> 6) << 3) + (blk & 7);       // XCD swizzle
    const int qt = (blk >> 3) & 7;
    const int b = bh >> 3, h = bh & 7;
    const int qbase = qt * 128 + wave * 32;
    const size_t bhL = (size_t)bh * 1024;

    const bf16x8 qfA = *(const bf16x8*)&Q[(bhL + qbase + l15) * 32 + quad * 8];
    const bf16x8 qfB = *(const bf16x8*)&Q[(bhL + qbase + 16 + l15) * 32 + quad * 8];
    const float* brow0 = RBs + (size_t)h * 3969
                         + (32 - (qbase >> 5)) * 32 + 32 - l15 + quad * 4;
    const int srow = lane >> 2;
    const int sgcol = (lane & 3) ^ ((lane >> 3) & 3);
    const u16* ksrc = &Kb[bhL * 32];
    const u16* vsrc_lo = &Vt[(((size_t)bh * 32) + srow) << 10];
    const u16* vsrc_hi = &Vt[(((size_t)bh * 32) + 16 + srow) << 10];

    f32x4 oA_lo{0.f, 0.f, 0.f, 0.f}, oA_hi{0.f, 0.f, 0.f, 0.f};
    f32x4 oB_lo{0.f, 0.f, 0.f, 0.f}, oB_hi{0.f, 0.f, 0.f, 0.f};
    f32x4 sacA{0.f, 0.f, 0.f, 0.f}, sacB{0.f, 0.f, 0.f, 0.f};  // denom: row=quad*4+r == q row
    const bf16 one1 = (bf16)1.f;
    const bf16x4 onesb = {one1, one1, one1, one1};

    const int swz = (l15 >> 1) & 3;
    const int kcol = (quad ^ swz) * 8;
    const int g0 = (2 * ((quad >> 1) ^ swz) + (quad & 1)) * 4;
    const int g1 = (2 * (((quad >> 1) + 2) ^ swz) + (quad & 1)) * 4;

    // bias prefetch registers: set X used by COMPUTE of tile X's chunks
    f32x4u bmA, b0A, b1A, bmB, b0B, b1B;

#define BLOADA(c) do {                                          \
        bmA = *(const f32x4u*)(brow0 + (c) * 32 - 16);          \
        b0A = *(const f32x4u*)(brow0 + (c) * 32);               \
        b1A = *(const f32x4u*)(brow0 + (c) * 32 + 16);          \
    } while (0)
#define BLOADB(c) do {                                          \
        bmB = *(const f32x4u*)(brow0 + (c) * 32 - 16);          \
        b0B = *(const f32x4u*)(brow0 + (c) * 32);               \
        b1B = *(const f32x4u*)(brow0 + (c) * 32 + 16);          \
    } while (0)

#define STAGE(buf, c) do {                                                              \
        const int kb_ = (c) * 32;                                                       \
        async_cp16(ksrc + kb_ * 32 + srow * 32 + sgcol * 8, &kbuf[wave][buf][0]);       \
        async_cp16(ksrc + kb_ * 32 + 512 + srow * 32 + sgcol * 8, &kbuf[wave][buf][512]); \
        async_cp16(vsrc_lo + kb_ + sgcol * 8, &vbuf[wave][buf][0]);                     \
        async_cp16(vsrc_hi + kb_ + sgcol * 8, &vbuf[wave][buf][512]);                   \
    } while (0)

// Bias rides in as the QK^T C-operand (R19): s?[r] = qk + bias[r].
// Denominator (R20): sac += P^T * ones via pv_mfma, accumulated across chunks.
// R25: setprio(1) during the MFMA/exp2 burst.
#define COMPUTE(cur, BM, B0, B1) do {                                                     \
        const bf16x8 kf0 = *(const bf16x8*)&kbuf[wave][cur][l15 * 32 + kcol];             \
        const bf16x8 kf1 = *(const bf16x8*)&kbuf[wave][cur][(16 + l15) * 32 + kcol];      \
        const bf16x4 v00 = __builtin_bit_cast(bf16x4, *(const u16x4*)&vbuf[wave][cur][l15 * 32 + g0]); \
        const bf16x4 v10 = __builtin_bit_cast(bf16x4, *(const u16x4*)&vbuf[wave][cur][l15 * 32 + g1]); \
        const bf16x4 v01 = __builtin_bit_cast(bf16x4, *(const u16x4*)&vbuf[wave][cur][(16 + l15) * 32 + g0]); \
        const bf16x4 v11 = __builtin_bit_cast(bf16x4, *(const u16x4*)&vbuf[wave][cur][(16 + l15) * 32 + g1]); \
        const f32x4 cb0 = f32x4{(B0)[0], (B0)[1], (B0)[2], (B0)[3]};                      \
        const f32x4 cb1 = f32x4{(B1)[0], (B1)[1], (B1)[2], (B1)[3]};                      \
        const f32x4 cbm = f32x4{(BM)[0], (BM)[1], (BM)[2], (BM)[3]};                      \
        __builtin_amdgcn_s_setprio(1);                                                    \
        f32x4 s0A = __builtin_amdgcn_mfma_f32_16x16x32_bf16(kf0, qfA, cb0, 0, 0, 0);      \
        f32x4 s1A = __builtin_amdgcn_mfma_f32_16x16x32_bf16(kf1, qfA, cb1, 0, 0, 0);      \
        f32x4 s0B = __builtin_amdgcn_mfma_f32_16x16x32_bf16(kf0, qfB, cbm, 0, 0, 0);      \
        f32x4 s1B = __builtin_amdgcn_mfma_f32_16x16x32_bf16(kf1, qfB, cb0, 0, 0, 0);      \
        bf16x4 p0A, p1A, p0B, p1B;                                                        \
        _Pragma("unroll")                                                                 \
        for (int r = 0; r < 4; r++) {                                                     \
            p0A[r] = (bf16)__builtin_amdgcn_exp2f(s0A[r]);                                \
            p1A[r] = (bf16)__builtin_amdgcn_exp2f(s1A[r]);                                \
            p0B[r] = (bf16)__builtin_amdgcn_exp2f(s0B[r]);                                \
            p1B[r] = (bf16)__builtin_amdgcn_exp2f(s1B[r]);                                \
        }                                                                                 \
        oA_lo = pv_mfma(p0A, v00, oA_lo);                                                 \
        oA_hi = pv_mfma(p0A, v01, oA_hi);                                                 \
        oA_lo = pv_mfma(p1A, v10, oA_lo);                                                 \
        oA_hi = pv_mfma(p1A, v11, oA_hi);                                                 \
        sacA = pv_mfma(p0A, onesb, sacA);                                                 \
        sacA = pv_mfma(p1A, onesb, sacA);                                                 \
        oB_lo = pv_mfma(p0B, v00, oB_lo);                                                 \
        oB_hi = pv_mfma(p0B, v01, oB_hi);                                                 \
        oB_lo = pv_mfma(p1B, v10, oB_lo);                                                 \
        oB_hi = pv_mfma(p1B, v11, oB_hi);                                                 \
        sacB = pv_mfma(p0B, onesb, sacB);                                                 \
        sacB = pv_mfma(p1B, onesb, sacB);                                                 \
        __builtin_amdgcn_s_setprio(0);                                                    \
    } while (0)

#define WAIT4 asm volatile("s_waitcnt vmcnt(4)" ::: "memory")
#define WAIT7 asm volatile("s_waitcnt vmcnt(7)" ::: "memory")
#define WAIT0 asm volatile("s_waitcnt vmcnt(0)" ::: "memory")
#define DSDRAIN asm volatile("s_waitcnt lgkmcnt(0)" ::: "memory")

    // prologue: bias(0),bias(1) issued before the stages so the first WAIT4 covers them
    BLOADA(0); BLOADB(1);
    STAGE(0, 0);
    STAGE(1, 1);
    // peel first pair: first wait is WAIT4, then steady-state WAIT7
    WAIT4; COMPUTE(0, bmA, b0A, b1A); DSDRAIN; BLOADA(2); STAGE(0, 2);
    WAIT7; COMPUTE(1, bmB, b0B, b1B); DSDRAIN; BLOADB(3); STAGE(1, 3);
    for (int c = 2; c < 28; c += 2) {
        WAIT7; COMPUTE(0, bmA, b0A, b1A); DSDRAIN; BLOADA(c + 2); STAGE(0, c + 2);
        WAIT7; COMPUTE(1, bmB, b0B, b1B); DSDRAIN; BLOADB(c + 3); STAGE(1, c + 3);
    }
    WAIT7; COMPUTE(0, bmA, b0A, b1A); DSDRAIN; BLOADA(30); STAGE(0, 30);
    WAIT7; COMPUTE(1, bmB, b0B, b1B); DSDRAIN; BLOADB(31); STAGE(1, 31);
    WAIT7; COMPUTE(0, bmA, b0A, b1A);
    WAIT0; COMPUTE(1, bmB, b0B, b1B);
#undef BLOADA
#undef BLOADB
#undef STAGE
#undef COMPUTE
#undef WAIT4
#undef WAIT7
#undef WAIT0
#undef DSDRAIN

    // sac[r] = full denominator for q row quad*4+r (replicated over l15) — direct reciprocal.
#pragma unroll
    for (int r = 0; r < 4; r++) {
        const float invA = 1.f / sacA[r];
        const float invB = 1.f / sacB[r];
        const int iA = qbase + quad * 4 + r;
        const int iB = iA + 16;
        O[((size_t)(b * 1024 + iA) * 256) + h * 32 + l15] = bfbits(oA_lo[r] * invA);
        O[((size_t)(b * 1024 + iA) * 256) + h * 32 + 16 + l15] = bfbits(oA_hi[r] * invA);
        O[((size_t)(b * 1024 + iB) * 256) + h * 32 + l15] = bfbits(oB_lo[r] * invB);
        O[((size_t)(b * 1024 + iB) * 256) + h * 32 + 16 + l15] = bfbits(oB_hi[r] * invB);
    }
}

extern "C" void kernel_launch(void* const* d_in, const int* in_sizes, int n_in,
                              void* d_out, int out_size, void* d_ws, size_t ws_size,
                              hipStream_t stream) {
    const float* x   = (const float*)d_in[0];
    const float* Qw  = (const float*)d_in[1];
    const float* Kw  = (const float*)d_in[2];
    const float* Vw  = (const float*)d_in[3];
    const float* Fw  = (const float*)d_in[4];
    const float* ffb = (const float*)d_in[5];
    const float* RB  = (const float*)d_in[6];
    // d_in[7] = rel_idx (int32): deterministic, computed analytically in-kernel.

    u16* ws = (u16*)d_ws;
    u16* xf = ws;                   // 8192 x 256 bf16 (4 MB)   ... later reused as ob
    u16* wt = xf + 2097152;         // 1024 x 256 bf16 (0.5 MB) [Qw^T|Kw^T|Vw^T|ffw^T]
    u16* q  = wt + 262144;          // (b,h,l,d)  bf16 (4 MB), pre-scaled by log2e
    u16* kk = q  + 2097152;         // (b,h,l,d)  bf16 (4 MB)
    u16* vt = kk + 2097152;         // (b,h,d,l)  bf16 (4 MB)
    float* RBs = (float*)(vt + 2097152);   // 8 x 3969 fp32 (127 KB), bias * log2e
    u16* ob = xf;                   // (b,l,h*32+d) bf16 — aliases xf (dead after V proj)

    prep<<<dim3(608), 256, 0, stream>>>(x, Qw, Kw, Vw, Fw, RB, xf, wt, RBs);
    gemm_fused<4, 0><<<dim3(768), 256, 0, stream>>>(xf, wt, q, kk, vt, nullptr, nullptr, nullptr); // QK + V^T
    attn<<<dim3(512), 256, 0, stream>>>(q, kk, vt, RBs, ob);
    gemm_fused<2, 2><<<dim3(512), 256, 0, stream>>>(xf, wt, q, kk, vt, ob, (float*)d_out, ffb);    // FF
}

// Round 10
// 117.143 us; speedup vs baseline: 1.1998x; 1.0105x over previous
//
#include <hip/hip_runtime.h>
#include <math.h>

// RelativeAttention on MI355X (gfx950). FP32 inputs/output; bf16 intermediates, fp32 accum.
// Round 26: byte-exact restore of the R20 optimum (116.35us, absmax 0.06640625). R25's
// s_setprio cost +2.0us (all waves run the same loop -> priority hint = pure overhead, m190
// regime not m191). Session ledger: wins were VALU-issue cuts in attn (R19 bias-as-C-operand
// -1.3us, R20 MFMA-pipe denominator -0.6us); all structural/latency/sync/priority changes
// null or negative (R17 dbuf, R18 bias prefetch, R21 shared staging, R22 prep float4,
// R23 zero-LDS, R24 depth-4, R25 setprio). attn residual is cross-XCD fabric latency
// (R23/R24 counters: both pipes ~85% idle, insensitive to pipeline depth); ~85us of the
// measured window is harness poison-fill. This is the practical floor of this decomposition.
// B=8, C=256, H=W=32 (L=1024), nh=8, dk=dv=32, OUT_C=256.

typedef unsigned short u16;
typedef __bf16 bf16;
typedef bf16 bf16x8 __attribute__((ext_vector_type(8)));
typedef bf16 bf16x4 __attribute__((ext_vector_type(4)));
typedef short s16x4 __attribute__((ext_vector_type(4)));
typedef float f32x4 __attribute__((ext_vector_type(4)));
typedef float f32x4u __attribute__((ext_vector_type(4), aligned(4)));
typedef u16 u16x8 __attribute__((ext_vector_type(8)));
typedef u16 u16x4 __attribute__((ext_vector_type(4)));

#define DEVI __device__ __forceinline__

DEVI u16 bfbits(float f) { return __builtin_bit_cast(u16, (bf16)f); }

DEVI void async_cp16(const u16* g, u16* l) {
    __builtin_amdgcn_global_load_lds((const __attribute__((address_space(1))) void*)g,
                                     (__attribute__((address_space(3))) void*)l, 16, 0, 0);
}

// 16x16x16 bf16 MFMA (K=16): A[m=lane&15][k=quad*4+j], B[k=quad*4+j][n=lane&15],
// C/D[row=quad*4+reg][col=lane&15]. (absmax-verified R7-R20.)
DEVI f32x4 pv_mfma(bf16x4 a, bf16x4 b, f32x4 c) {
#if __has_builtin(__builtin_amdgcn_mfma_f32_16x16x16bf16_1k)
    return __builtin_amdgcn_mfma_f32_16x16x16bf16_1k(
        __builtin_bit_cast(s16x4, a), __builtin_bit_cast(s16x4, b), c, 0, 0, 0);
#else
    asm("s_nop 1\n\tv_mfma_f32_16x16x16_bf16 %0, %1, %2, %0"
        : "+v"(c) : "v"(a), "v"(b));
    return c;
#endif
}

// ---------------- fused prep: transposes + bias prescale ----------------
__global__ __launch_bounds__(256) void prep(const float* __restrict__ X,
                                            const float* __restrict__ Qw, const float* __restrict__ Kw,
                                            const float* __restrict__ Vw, const float* __restrict__ Fw,
                                            const float* __restrict__ RB,
                                            u16* __restrict__ XF, u16* __restrict__ WT,
                                            float* __restrict__ RBs) {
    __shared__ u16 t[64 * 65];
    const int blk = blockIdx.x, tid = threadIdx.x;
    if (blk < 576) {
        const float* src;
        int cbase, rbase, rows_total;
        u16* dst;
        if (blk < 512) {
            const int b = blk >> 6;
            cbase = (blk & 3) * 64; rbase = ((blk >> 2) & 15) * 64;
            src = X + (size_t)b * 256 * 1024; dst = XF + (size_t)b * 1024 * 256;
            rows_total = 1024;
        } else {
            const int t2 = blk - 512, wsel = t2 >> 4;
            cbase = (t2 & 3) * 64; rbase = ((t2 >> 2) & 3) * 64;
            src = wsel == 0 ? Qw : wsel == 1 ? Kw : wsel == 2 ? Vw : Fw;
            dst = WT + (size_t)wsel * 256 * 256;
            rows_total = 256;
        }
        const int w = tid >> 6, r = tid & 63;
#pragma unroll
        for (int i = 0; i < 16; i++) {
            const int c = w * 16 + i;
            t[c * 65 + r] = bfbits(src[(size_t)(cbase + c) * rows_total + rbase + r]);
        }
        __syncthreads();
#pragma unroll
        for (int i = 0; i < 2; i++) {
            const int idx = i * 256 + tid;
            const int r2 = idx >> 3, cg = idx & 7;
            u16x8 v;
#pragma unroll
            for (int j = 0; j < 8; j++) v[j] = t[(cg * 8 + j) * 65 + r2];
            *(u16x8*)&dst[(size_t)(rbase + r2) * 256 + cbase + cg * 8] = v;
        }
    } else {
        const int n = 8 * 3969;
        for (int i = (blk - 576) * 256 + tid; i < n; i += 32 * 256)
            RBs[i] = RB[i] * 1.44269504f;
    }
}

// ---------------- unified GEMM: D[m][n] = sum_k A[m][k]*Bt[n][k], K=256, bf16 in ----------------
// Tile (MFR*32) x 64, BK=32; 4 waves as 2x2, wave = (MFR*16) x 32. async_cp16 staging +
// XOR-swizzled chunks (swizzle formulas are 64-row-period invariant).
// R17: double-buffered LDS, prefetch-then-compute, ONE __syncthreads per K-iter. Its implicit
// vmcnt(0)+lgkmcnt(0)+s_barrier guarantees (a) next buffer fully landed for all waves and
// (b) all waves finished ds_reads of the buffer overwritten next iter.
// PASS 0: blocks 0..511 mode 0 (xf*wt -> q,k), 512..767 mode 1 (Vw^T*xf -> v^T). MFR=4.
// PASS 2: FF (ffw^T*ob -> fp32 out + bias). MFR=2, 512 blocks.
template <int MFR, int PASS>
__global__ __launch_bounds__(256, 3) void gemm_fused(const u16* __restrict__ xf, const u16* __restrict__ wt,
                                                     u16* __restrict__ q, u16* __restrict__ kk,
                                                     u16* __restrict__ vt, const u16* __restrict__ ob,
                                                     float* __restrict__ outf, const float* __restrict__ ffb) {
    constexpr int TM = MFR * 32;                       // block M-span
    __shared__ __align__(16) u16 lA[2][TM * 32];
    __shared__ __align__(16) u16 lB[2][64 * 32];
    const int tid = threadIdx.x;
    const int wave = tid >> 6, lane = tid & 63;
    const int quad = lane >> 4, l15 = lane & 15;

    int mode, mbase, nbase;
    const u16 *A, *Bt;
    if (PASS == 2) {
        mode = 2; A = wt + 768 * 256; Bt = ob;               // M=256, N=8192
        mbase = (blockIdx.x & 3) * 64; nbase = (blockIdx.x >> 2) * 64;
    } else if (blockIdx.x < 512) {
        mode = 0; A = xf; Bt = wt;                            // M=8192, N=512
        mbase = (blockIdx.x >> 3) * TM; nbase = (blockIdx.x & 7) * 64;
    } else {
        mode = 1; A = wt + 512 * 256; Bt = xf;                // M=256, N=8192
        const int t = blockIdx.x - 512;
        mbase = (t & 1) * TM; nbase = (t >> 1) * 64;
    }

    const int m0 = (wave >> 1) * (MFR * 16), n0 = (wave & 1) * 32;
    const int srow = tid >> 2;                         // wave*16 + lane>>2: rows per 64-row half
    const int sgcol = (lane & 3) ^ ((lane >> 3) & 3);  // swizzled global chunk col (64-row invariant)
    const int kcol = ((quad ^ ((l15 >> 1) & 3))) * 8;  // reader chunk (16-row-base invariant)

    f32x4 acc[MFR][2];
#pragma unroll
    for (int i = 0; i < MFR; i++)
#pragma unroll
        for (int j = 0; j < 2; j++) acc[i][j] = f32x4{0.f, 0.f, 0.f, 0.f};

    // prologue: stage K-tile 0 into buffer 0, drain, barrier
#pragma unroll
    for (int half = 0; half < MFR / 2; half++)
        async_cp16(&A[(size_t)(mbase + half * 64 + srow) * 256 + sgcol * 8],
                   &lA[0][half * 2048 + wave * 512]);
    async_cp16(&Bt[(size_t)(nbase + srow) * 256 + sgcol * 8], &lB[0][wave * 512]);
    __syncthreads();

#pragma unroll
    for (int t = 0; t < 8; ++t) {
        const int cur = t & 1;
        if (t < 7) {                                    // prefetch next K-tile into the other buffer
            const int kb = (t + 1) * 32;
#pragma unroll
            for (int half = 0; half < MFR / 2; half++)
                async_cp16(&A[(size_t)(mbase + half * 64 + srow) * 256 + kb + sgcol * 8],
                           &lA[cur ^ 1][half * 2048 + wave * 512]);
            async_cp16(&Bt[(size_t)(nbase + srow) * 256 + kb + sgcol * 8], &lB[cur ^ 1][wave * 512]);
        }
        bf16x8 af[MFR], bfr[2];
#pragma unroll
        for (int i = 0; i < MFR; i++) af[i] = *(const bf16x8*)&lA[cur][(m0 + i * 16 + l15) * 32 + kcol];
#pragma unroll
        for (int j = 0; j < 2; j++) bfr[j] = *(const bf16x8*)&lB[cur][(n0 + j * 16 + l15) * 32 + kcol];
#pragma unroll
        for (int i = 0; i < MFR; i++)
#pragma unroll
            for (int j = 0; j < 2; j++)
                acc[i][j] = __builtin_amdgcn_mfma_f32_16x16x32_bf16(af[i], bfr[j], acc[i][j], 0, 0, 0);
        __syncthreads();   // vmcnt(0)+lgkmcnt(0)+barrier: next buffer ready, reads of cur done
    }

    // epilogue: C-layout col = lane&15, row = quad*4 + reg
#pragma unroll
    for (int i = 0; i < MFR; i++) {
#pragma unroll
        for (int j = 0; j < 2; j++) {
#pragma unroll
            for (int r = 0; r < 4; r++) {
                const int gm = mbase + m0 + i * 16 + quad * 4 + r;
                const int gn = nbase + n0 + j * 16 + l15;
                float v = acc[i][j][r];
                if (mode == 0) {
                    const int b = gm >> 10, l = gm & 1023;
                    int n = gn;
                    u16* dst = q;
                    if (n >= 256) { n -= 256; dst = kk; }
                    else v *= 1.44269504f;                 // fold log2e into q
                    const int h = n >> 5, d = n & 31;
                    dst[(((size_t)(b * 8 + h) * 1024 + l) << 5) + d] = bfbits(v);
                } else if (mode == 1) {
                    const int h = gm >> 5, d = gm & 31;
                    const int b = gn >> 10, l = gn & 1023;
                    vt[(((size_t)(b * 8 + h) * 32 + d) << 10) + l] = bfbits(v);
                } else {
                    const int b = gn >> 10, l = gn & 1023;
                    outf[(((size_t)(b * 256 + gm)) << 10) + l] = v + ffb[gm];
                }
            }
        }
    }
}

// ---------------- flash attention: 2 Q-tiles per wave, barrier-free depth-2 pipeline ----------
// 512 blocks x 4 waves x 32 q-rows. Per-wave private K/V LDS double-buffers, XOR swizzle,
// STAGE-after-COMPUTE + lgkm drain. Bias identity b1(tileB)==b0(tileA).
// R18: bias prefetched one chunk ahead (vmcnt(7) steady state). R19: bias as QK^T C-operand.
// R20: denominator via pv_mfma(p, ones, sac) — MFMA-pipe row-sum, no VALU adds, no shfls.
__global__ __launch_bounds__(256, 2) void attn(const u16* __restrict__ Q, const u16* __restrict__ Kb,
                                               const u16* __restrict__ Vt, const float* __restrict__ RBs,
                                               u16* __restrict__ O) {
    __shared__ __align__(16) u16 kbuf[4][2][32 * 32];
    __shared__ __align__(16) u16 vbuf[4][2][32 * 32];
    const int tid = threadIdx.x;
    const int wave = tid >> 6, lane = tid & 63;
    const int quad = lane >> 4, l15 = lane & 15;
    const int blk = blockIdx.x;
    const int bh = ((blk >> 6) << 3) + (blk & 7);       // XCD swizzle
    const int qt = (blk >> 3) & 7;
    const int b = bh >> 3, h = bh & 7;
    const int qbase = qt * 128 + wave * 32;
    const size_t bhL = (size_t)bh * 1024;

    const bf16x8 qfA = *(const bf16x8*)&Q[(bhL + qbase + l15) * 32 + quad * 8];
    const bf16x8 qfB = *(const bf16x8*)&Q[(bhL + qbase + 16 + l15) * 32 + quad * 8];
    const float* brow0 = RBs + (size_t)h * 3969
                         + (32 - (qbase >> 5)) * 32 + 32 - l15 + quad * 4;
    const int srow = lane >> 2;
    const int sgcol = (lane & 3) ^ ((lane >> 3) & 3);
    const u16* ksrc = &Kb[bhL * 32];
    const u16* vsrc_lo = &Vt[(((size_t)bh * 32) + srow) << 10];
    const u16* vsrc_hi = &Vt[(((size_t)bh * 32) + 16 + srow) << 10];

    f32x4 oA_lo{0.f, 0.f, 0.f, 0.f}, oA_hi{0.f, 0.f, 0.f, 0.f};
    f32x4 oB_lo{0.f, 0.f, 0.f, 0.f}, oB_hi{0.f, 0.f, 0.f, 0.f};
    f32x4 sacA{0.f, 0.f, 0.f, 0.f}, sacB{0.f, 0.f, 0.f, 0.f};  // denom: row=quad*4+r == q row
    const bf16 one1 = (bf16)1.f;
    const bf16x4 onesb = {one1, one1, one1, one1};

    const int swz = (l15 >> 1) & 3;
    const int kcol = (quad ^ swz) * 8;
    const int g0 = (2 * ((quad >> 1) ^ swz) + (quad & 1)) * 4;
    const int g1 = (2 * (((quad >> 1) + 2) ^ swz) + (quad & 1)) * 4;

    // bias prefetch registers: set X used by COMPUTE of tile X's chunks
    f32x4u bmA, b0A, b1A, bmB, b0B, b1B;

#define BLOADA(c) do {                                          \
        bmA = *(const f32x4u*)(brow0 + (c) * 32 - 16);          \
        b0A = *(const f32x4u*)(brow0 + (c) * 32);               \
        b1A = *(const f32x4u*)(brow0 + (c) * 32 + 16);          \
    } while (0)
#define BLOADB(c) do {                                          \
        bmB = *(const f32x4u*)(brow0 + (c) * 32 - 16);          \
        b0B = *(const f32x4u*)(brow0 + (c) * 32);               \
        b1B = *(const f32x4u*)(brow0 + (c) * 32 + 16);          \
    } while (0)

#define STAGE(buf, c) do {                                                              \
        const int kb_ = (c) * 32;                                                       \
        async_cp16(ksrc + kb_ * 32 + srow * 32 + sgcol * 8, &kbuf[wave][buf][0]);       \
        async_cp16(ksrc + kb_ * 32 + 512 + srow * 32 + sgcol * 8, &kbuf[wave][buf][512]); \
        async_cp16(vsrc_lo + kb_ + sgcol * 8, &vbuf[wave][buf][0]);                     \
        async_cp16(vsrc_hi + kb_ + sgcol * 8, &vbuf[wave][buf][512]);                   \
    } while (0)

// Bias rides in as the QK^T C-operand (R19): s?[r] = qk + bias[r].
// Denominator (R20): sac += P^T * ones via pv_mfma — C[row=quad*4+r][col] = sum_k P[k][row],
// replicated over cols; accumulated across chunks. No VALU adds, no cross-lane reduction.
#define COMPUTE(cur, BM, B0, B1) do {                                                     \
        const bf16x8 kf0 = *(const bf16x8*)&kbuf[wave][cur][l15 * 32 + kcol];             \
        const bf16x8 kf1 = *(const bf16x8*)&kbuf[wave][cur][(16 + l15) * 32 + kcol];      \
        const bf16x4 v00 = __builtin_bit_cast(bf16x4, *(const u16x4*)&vbuf[wave][cur][l15 * 32 + g0]); \
        const bf16x4 v10 = __builtin_bit_cast(bf16x4, *(const u16x4*)&vbuf[wave][cur][l15 * 32 + g1]); \
        const bf16x4 v01 = __builtin_bit_cast(bf16x4, *(const u16x4*)&vbuf[wave][cur][(16 + l15) * 32 + g0]); \
        const bf16x4 v11 = __builtin_bit_cast(bf16x4, *(const u16x4*)&vbuf[wave][cur][(16 + l15) * 32 + g1]); \
        const f32x4 cb0 = f32x4{(B0)[0], (B0)[1], (B0)[2], (B0)[3]};                      \
        const f32x4 cb1 = f32x4{(B1)[0], (B1)[1], (B1)[2], (B1)[3]};                      \
        const f32x4 cbm = f32x4{(BM)[0], (BM)[1], (BM)[2], (BM)[3]};                      \
        f32x4 s0A = __builtin_amdgcn_mfma_f32_16x16x32_bf16(kf0, qfA, cb0, 0, 0, 0);      \
        f32x4 s1A = __builtin_amdgcn_mfma_f32_16x16x32_bf16(kf1, qfA, cb1, 0, 0, 0);      \
        f32x4 s0B = __builtin_amdgcn_mfma_f32_16x16x32_bf16(kf0, qfB, cbm, 0, 0, 0);      \
        f32x4 s1B = __builtin_amdgcn_mfma_f32_16x16x32_bf16(kf1, qfB, cb0, 0, 0, 0);      \
        bf16x4 p0A, p1A, p0B, p1B;                                                        \
        _Pragma("unroll")                                                                 \
        for (int r = 0; r < 4; r++) {                                                     \
            p0A[r] = (bf16)__builtin_amdgcn_exp2f(s0A[r]);                                \
            p1A[r] = (bf16)__builtin_amdgcn_exp2f(s1A[r]);                                \
            p0B[r] = (bf16)__builtin_amdgcn_exp2f(s0B[r]);                                \
            p1B[r] = (bf16)__builtin_amdgcn_exp2f(s1B[r]);                                \
        }                                                                                 \
        oA_lo = pv_mfma(p0A, v00, oA_lo);                                                 \
        oA_hi = pv_mfma(p0A, v01, oA_hi);                                                 \
        oA_lo = pv_mfma(p1A, v10, oA_lo);                                                 \
        oA_hi = pv_mfma(p1A, v11, oA_hi);                                                 \
        sacA = pv_mfma(p0A, onesb, sacA);                                                 \
        sacA = pv_mfma(p1A, onesb, sacA);                                                 \
        oB_lo = pv_mfma(p0B, v00, oB_lo);                                                 \
        oB_hi = pv_mfma(p0B, v01, oB_hi);                                                 \
        oB_lo = pv_mfma(p1B, v10, oB_lo);                                                 \
        oB_hi = pv_mfma(p1B, v11, oB_hi);                                                 \
        sacB = pv_mfma(p0B, onesb, sacB);                                                 \
        sacB = pv_mfma(p1B, onesb, sacB);                                                 \
    } while (0)

#define WAIT4 asm volatile("s_waitcnt vmcnt(4)" ::: "memory")
#define WAIT7 asm volatile("s_waitcnt vmcnt(7)" ::: "memory")
#define WAIT0 asm volatile("s_waitcnt vmcnt(0)" ::: "memory")
#define DSDRAIN asm volatile("s_waitcnt lgkmcnt(0)" ::: "memory")

    // prologue: bias(0),bias(1) issued before the stages so the first WAIT4 covers them
    BLOADA(0); BLOADB(1);
    STAGE(0, 0);
    STAGE(1, 1);
    // peel first pair: first wait is WAIT4, then steady-state WAIT7
    WAIT4; COMPUTE(0, bmA, b0A, b1A); DSDRAIN; BLOADA(2); STAGE(0, 2);
    WAIT7; COMPUTE(1, bmB, b0B, b1B); DSDRAIN; BLOADB(3); STAGE(1, 3);
    for (int c = 2; c < 28; c += 2) {
        WAIT7; COMPUTE(0, bmA, b0A, b1A); DSDRAIN; BLOADA(c + 2); STAGE(0, c + 2);
        WAIT7; COMPUTE(1, bmB, b0B, b1B); DSDRAIN; BLOADB(c + 3); STAGE(1, c + 3);
    }
    WAIT7; COMPUTE(0, bmA, b0A, b1A); DSDRAIN; BLOADA(30); STAGE(0, 30);
    WAIT7; COMPUTE(1, bmB, b0B, b1B); DSDRAIN; BLOADB(31); STAGE(1, 31);
    WAIT7; COMPUTE(0, bmA, b0A, b1A);
    WAIT0; COMPUTE(1, bmB, b0B, b1B);
#undef BLOADA
#undef BLOADB
#undef STAGE
#undef COMPUTE
#undef WAIT4
#undef WAIT7
#undef WAIT0
#undef DSDRAIN

    // sac[r] = full denominator for q row quad*4+r (replicated over l15) — direct reciprocal.
#pragma unroll
    for (int r = 0; r < 4; r++) {
        const float invA = 1.f / sacA[r];
        const float invB = 1.f / sacB[r];
        const int iA = qbase + quad * 4 + r;
        const int iB = iA + 16;
        O[((size_t)(b * 1024 + iA) * 256) + h * 32 + l15] = bfbits(oA_lo[r] * invA);
        O[((size_t)(b * 1024 + iA) * 256) + h * 32 + 16 + l15] = bfbits(oA_hi[r] * invA);
        O[((size_t)(b * 1024 + iB) * 256) + h * 32 + l15] = bfbits(oB_lo[r] * invB);
        O[((size_t)(b * 1024 + iB) * 256) + h * 32 + 16 + l15] = bfbits(oB_hi[r] * invB);
    }
}

extern "C" void kernel_launch(void* const* d_in, const int* in_sizes, int n_in,
                              void* d_out, int out_size, void* d_ws, size_t ws_size,
                              hipStream_t stream) {
    const float* x   = (const float*)d_in[0];
    const float* Qw  = (const float*)d_in[1];
    const float* Kw  = (const float*)d_in[2];
    const float* Vw  = (const float*)d_in[3];
    const float* Fw  = (const float*)d_in[4];
    const float* ffb = (const float*)d_in[5];
    const float* RB  = (const float*)d_in[6];
    // d_in[7] = rel_idx (int32): deterministic, computed analytically in-kernel.

    u16* ws = (u16*)d_ws;
    u16* xf = ws;                   // 8192 x 256 bf16 (4 MB)   ... later reused as ob
    u16* wt = xf + 2097152;         // 1024 x 256 bf16 (0.5 MB) [Qw^T|Kw^T|Vw^T|ffw^T]
    u16* q  = wt + 262144;          // (b,h,l,d)  bf16 (4 MB), pre-scaled by log2e
    u16* kk = q  + 2097152;         // (b,h,l,d)  bf16 (4 MB)
    u16* vt = kk + 2097152;         // (b,h,d,l)  bf16 (4 MB)
    float* RBs = (float*)(vt + 2097152);   // 8 x 3969 fp32 (127 KB), bias * log2e
    u16* ob = xf;                   // (b,l,h*32+d) bf16 — aliases xf (dead after V proj)

    prep<<<dim3(608), 256, 0, stream>>>(x, Qw, Kw, Vw, Fw, RB, xf, wt, RBs);
    gemm_fused<4, 0><<<dim3(768), 256, 0, stream>>>(xf, wt, q, kk, vt, nullptr, nullptr, nullptr); // QK + V^T
    attn<<<dim3(512), 256, 0, stream>>>(q, kk, vt, RBs, ob);
    gemm_fused<2, 2><<<dim3(512), 256, 0, stream>>>(xf, wt, q, kk, vt, ob, (float*)d_out, ffb);    // FF
}